// Round 5
// baseline (95.156 us; speedup 1.0000x reference)
//
#include <hip/hip_runtime.h>
#include <math.h>

#define BB 16
#define NN 96
#define HH 256
#define NBIN 11

// ---------------------------------------------------------------------------
// Kernel 1: proj[r][k] = sum_h inputs[r][h] * W_atom[h][k] + 0.5*b_bin[k]
//   4 rows/block -> 384 blocks (1.5 blocks/CU) for latency hiding;
//   W_atom (256 KB) stays L2-resident.
// ---------------------------------------------------------------------------
#define ROWS_PER_BLOCK 4

__global__ __launch_bounds__(HH) void proj_kernel(
    const float* __restrict__ inputs,
    const float* __restrict__ W_atom,
    const float* __restrict__ b_bin,
    float* __restrict__ proj)
{
    __shared__ float rows[ROWS_PER_BLOCK][HH];
    const int r0 = blockIdx.x * ROWS_PER_BLOCK;
    const int k  = threadIdx.x;

    #pragma unroll
    for (int r = 0; r < ROWS_PER_BLOCK; ++r)
        rows[r][k] = inputs[(size_t)(r0 + r) * HH + k];
    __syncthreads();

    float acc[ROWS_PER_BLOCK];
    #pragma unroll
    for (int r = 0; r < ROWS_PER_BLOCK; ++r) acc[r] = 0.f;

    #pragma unroll 8
    for (int h = 0; h < HH; ++h) {
        const float w = W_atom[(size_t)h * HH + k];   // coalesced over k
        #pragma unroll
        for (int r = 0; r < ROWS_PER_BLOCK; ++r)
            acc[r] = fmaf(rows[r][h], w, acc[r]);     // LDS broadcast read
    }

    const float halfb = 0.5f * b_bin[k];
    #pragma unroll
    for (int r = 0; r < ROWS_PER_BLOCK; ++r)
        proj[(size_t)(r0 + r) * HH + k] = acc[r] + halfb;
}

// ---------------------------------------------------------------------------
// Kernel 2a: pure streaming writer. atom_pair[bi][j][k] = in_i[k] + in_j[k].
//   One block per bi; plain float4 stores (LLC can absorb the 151 MB
//   working set across graph replays). Nothing else in the kernel, so the
//   store queue is the only limiter.
// ---------------------------------------------------------------------------
__global__ __launch_bounds__(256) void pair_writer(
    const float* __restrict__ inputs,
    float* __restrict__ atom_pair)
{
    const int bi   = blockIdx.x;           // b*N + i
    const int b    = bi / NN;
    const int lane = threadIdx.x & 63;
    const int wave = threadIdx.x >> 6;
    const int k4   = lane << 2;

    const float4 in_i = *(const float4*)(inputs + (size_t)bi * HH + k4);
    const float* base = inputs + (size_t)b * NN * HH + k4;
    float*       out  = atom_pair + (size_t)bi * NN * HH + k4;

    for (int j = wave; j < NN; j += 4) {
        const float4 in_j = *(const float4*)(base + (size_t)j * HH);
        float4 ap;
        ap.x = in_i.x + in_j.x;  ap.y = in_i.y + in_j.y;
        ap.z = in_i.z + in_j.z;  ap.w = in_i.w + in_j.w;
        *(float4*)(out + (size_t)j * HH) = ap;
    }
}

// ---------------------------------------------------------------------------
// Kernel 2b: score + context, no bulk stores. One block per bi; 4 waves;
//   wave owns j in {wave, wave+4, ...}, manually unrolled 2x so two
//   independent 6-step shfl-reduce chains overlap.
// ---------------------------------------------------------------------------
__global__ __launch_bounds__(256) void score_ctx_kernel(
    const float* __restrict__ inputs,
    const float* __restrict__ bin_features,
    const float* __restrict__ W_bin,
    const float* __restrict__ w_score,
    const float* __restrict__ b_score,
    const float* __restrict__ proj,
    float* __restrict__ context)
{
    const int bi   = blockIdx.x;           // b*N + i
    const int b    = bi / NN;
    const int lane = threadIdx.x & 63;
    const int wave = threadIdx.x >> 6;     // 0..3
    const int k4   = lane << 2;

    __shared__ float binf[NN * NBIN];      // 4224 B contiguous bin rows
    __shared__ float partial[3][HH];

    {
        const float* bp = bin_features + (size_t)bi * NN * NBIN;
        for (int t = threadIdx.x; t < NN * NBIN; t += 256)
            binf[t] = bp[t];
    }

    const float4 in_base_i = *(const float4*)(inputs + (size_t)bi * HH + k4);
    (void)in_base_i; // not needed here; context uses in_j only
    const float4 pr_i = *(const float4*)(proj + (size_t)bi * HH + k4);
    const float4 ws   = *(const float4*)(w_score + k4);
    const float  bsc  = b_score[0];

    float4 wb[NBIN];
    #pragma unroll
    for (int c = 0; c < NBIN; ++c)
        wb[c] = *(const float4*)(W_bin + c * HH + k4);

    const float* inb = inputs + (size_t)b * NN * HH + k4;
    const float* prb = proj   + (size_t)b * NN * HH + k4;

    __syncthreads();                       // binf ready

    float4 acc = make_float4(0.f, 0.f, 0.f, 0.f);

    // 96 / (4 waves * 2 unroll) = 12 iterations
    for (int t = 0; t < 12; ++t) {
        const int j1 = wave + 8 * t;
        const int j2 = j1 + 4;

        const float4 in1 = *(const float4*)(inb + (size_t)j1 * HH);
        const float4 pr1 = *(const float4*)(prb + (size_t)j1 * HH);
        const float4 in2 = *(const float4*)(inb + (size_t)j2 * HH);
        const float4 pr2 = *(const float4*)(prb + (size_t)j2 * HH);

        float4 v1, v2;
        v1.x = pr_i.x + pr1.x;  v1.y = pr_i.y + pr1.y;
        v1.z = pr_i.z + pr1.z;  v1.w = pr_i.w + pr1.w;
        v2.x = pr_i.x + pr2.x;  v2.y = pr_i.y + pr2.y;
        v2.z = pr_i.z + pr2.z;  v2.w = pr_i.w + pr2.w;

        const float* bf1 = &binf[j1 * NBIN];
        const float* bf2 = &binf[j2 * NBIN];
        #pragma unroll
        for (int c = 0; c < NBIN; ++c) {
            const float b1 = bf1[c];       // LDS broadcast
            const float b2 = bf2[c];
            v1.x = fmaf(b1, wb[c].x, v1.x);
            v1.y = fmaf(b1, wb[c].y, v1.y);
            v1.z = fmaf(b1, wb[c].z, v1.z);
            v1.w = fmaf(b1, wb[c].w, v1.w);
            v2.x = fmaf(b2, wb[c].x, v2.x);
            v2.y = fmaf(b2, wb[c].y, v2.y);
            v2.z = fmaf(b2, wb[c].z, v2.z);
            v2.w = fmaf(b2, wb[c].w, v2.w);
        }
        v1.x = fmaxf(v1.x, 0.f); v1.y = fmaxf(v1.y, 0.f);
        v1.z = fmaxf(v1.z, 0.f); v1.w = fmaxf(v1.w, 0.f);
        v2.x = fmaxf(v2.x, 0.f); v2.y = fmaxf(v2.y, 0.f);
        v2.z = fmaxf(v2.z, 0.f); v2.w = fmaxf(v2.w, 0.f);

        float t1 = v1.x * ws.x + v1.y * ws.y + v1.z * ws.z + v1.w * ws.w;
        float t2 = v2.x * ws.x + v2.y * ws.y + v2.z * ws.z + v2.w * ws.w;
        #pragma unroll
        for (int off = 32; off > 0; off >>= 1) {
            t1 += __shfl_xor(t1, off, 64); // two independent chains
            t2 += __shfl_xor(t2, off, 64);
        }

        const float s1 = 1.f / (1.f + expf(-(t1 + bsc)));
        const float s2 = 1.f / (1.f + expf(-(t2 + bsc)));
        acc.x = fmaf(s1, in1.x, acc.x);  acc.x = fmaf(s2, in2.x, acc.x);
        acc.y = fmaf(s1, in1.y, acc.y);  acc.y = fmaf(s2, in2.y, acc.y);
        acc.z = fmaf(s1, in1.z, acc.z);  acc.z = fmaf(s2, in2.z, acc.z);
        acc.w = fmaf(s1, in1.w, acc.w);  acc.w = fmaf(s2, in2.w, acc.w);
    }

    if (wave > 0) *(float4*)(&partial[wave - 1][k4]) = acc;
    __syncthreads();
    if (wave == 0) {
        #pragma unroll
        for (int w = 0; w < 3; ++w) {
            const float4 pw = *(const float4*)(&partial[w][k4]);
            acc.x += pw.x; acc.y += pw.y; acc.z += pw.z; acc.w += pw.w;
        }
        *(float4*)(context + (size_t)bi * HH + k4) = acc;
    }
}

extern "C" void kernel_launch(void* const* d_in, const int* in_sizes, int n_in,
                              void* d_out, int out_size, void* d_ws, size_t ws_size,
                              hipStream_t stream)
{
    const float* inputs       = (const float*)d_in[0];   // (B,N,H)
    const float* bin_features = (const float*)d_in[1];   // (B,N,N,BIN)
    const float* W_atom       = (const float*)d_in[2];   // (H,H)
    const float* W_bin        = (const float*)d_in[3];   // (BIN,H)
    const float* b_bin        = (const float*)d_in[4];   // (H,)
    const float* w_score      = (const float*)d_in[5];   // (H,1)
    const float* b_score      = (const float*)d_in[6];   // (1,)

    float* context   = (float*)d_out;                         // B*N*H
    float* atom_pair = (float*)d_out + (size_t)BB * NN * HH;  // B*N*N*H

    float* proj = (float*)d_ws;                               // B*N*H floats

    proj_kernel<<<(BB * NN) / ROWS_PER_BLOCK, HH, 0, stream>>>(
        inputs, W_atom, b_bin, proj);

    pair_writer<<<BB * NN, 256, 0, stream>>>(inputs, atom_pair);

    score_ctx_kernel<<<BB * NN, 256, 0, stream>>>(
        inputs, bin_features, W_bin, w_score, b_score, proj, context);
}

// Round 6
// 55.336 us; speedup vs baseline: 1.7196x; 1.7196x over previous
//
#include <hip/hip_runtime.h>
#include <math.h>

#define BB 16
#define NN 96
#define HH 256
#define NBIN 11

// ---------------------------------------------------------------------------
// Kernel 1: proj[r][k] = sum_h inputs[r][h] * W_atom[h][k] + 0.5*b_bin[k]
// ---------------------------------------------------------------------------
#define ROWS_PER_BLOCK 4

__global__ __launch_bounds__(HH) void proj_kernel(
    const float* __restrict__ inputs,
    const float* __restrict__ W_atom,
    const float* __restrict__ b_bin,
    float* __restrict__ proj)
{
    __shared__ float rows[ROWS_PER_BLOCK][HH];
    const int r0 = blockIdx.x * ROWS_PER_BLOCK;
    const int k  = threadIdx.x;

    #pragma unroll
    for (int r = 0; r < ROWS_PER_BLOCK; ++r)
        rows[r][k] = inputs[(size_t)(r0 + r) * HH + k];
    __syncthreads();

    float acc[ROWS_PER_BLOCK];
    #pragma unroll
    for (int r = 0; r < ROWS_PER_BLOCK; ++r) acc[r] = 0.f;

    #pragma unroll 8
    for (int h = 0; h < HH; ++h) {
        const float w = W_atom[(size_t)h * HH + k];   // coalesced over k
        #pragma unroll
        for (int r = 0; r < ROWS_PER_BLOCK; ++r)
            acc[r] = fmaf(rows[r][h], w, acc[r]);     // LDS broadcast read
    }

    const float halfb = 0.5f * b_bin[k];
    #pragma unroll
    for (int r = 0; r < ROWS_PER_BLOCK; ++r)
        proj[(size_t)(r0 + r) * HH + k] = acc[r] + halfb;
}

// ---------------------------------------------------------------------------
// Kernel 2 (fused pair + score + context): one block per (b,i); 4 waves;
//   wave owns j = wave + 4*u + 16*t, processing FOUR j's per outer step so
//   four independent shfl-butterfly chains overlap (hides DS latency).
//   Stores are plain float4 (LLC-absorbable), fully overlapped with compute.
// ---------------------------------------------------------------------------
__global__ __launch_bounds__(256) void pair_ctx_kernel(
    const float* __restrict__ inputs,
    const float* __restrict__ bin_features,
    const float* __restrict__ W_bin,
    const float* __restrict__ w_score,
    const float* __restrict__ b_score,
    const float* __restrict__ proj,
    float* __restrict__ atom_pair,
    float* __restrict__ context)
{
    const int bi   = blockIdx.x;           // b*N + i
    const int b    = bi / NN;
    const int lane = threadIdx.x & 63;
    const int wave = threadIdx.x >> 6;     // 0..3
    const int k4   = lane << 2;            // float4 offset into H

    __shared__ float binf[NN * NBIN];      // 4224 B contiguous bin rows
    __shared__ float partial[3][HH];

    {
        const float* bp = bin_features + (size_t)bi * NN * NBIN;
        for (int t = threadIdx.x; t < NN * NBIN; t += 256)
            binf[t] = bp[t];
    }

    const float4 in_i = *(const float4*)(inputs + (size_t)bi * HH + k4);
    const float4 pr_i = *(const float4*)(proj   + (size_t)bi * HH + k4);
    const float4 ws   = *(const float4*)(w_score + k4);
    const float  bsc  = b_score[0];

    float4 wb[NBIN];
    #pragma unroll
    for (int c = 0; c < NBIN; ++c)
        wb[c] = *(const float4*)(W_bin + c * HH + k4);

    const float* inb = inputs + (size_t)b * NN * HH + k4;
    const float* prb = proj   + (size_t)b * NN * HH + k4;
    float*       apb = atom_pair + (size_t)bi * NN * HH + k4;

    __syncthreads();                       // binf ready

    float4 acc = make_float4(0.f, 0.f, 0.f, 0.f);

    // 96 = 4 waves * 4 unroll * 6 outer steps
    for (int t = 0; t < 6; ++t) {
        const int j0 = wave + 16 * t;      // this wave's first j of the group

        float4 inj[4], prj[4];
        #pragma unroll
        for (int u = 0; u < 4; ++u) {
            inj[u] = *(const float4*)(inb + (size_t)(j0 + 4 * u) * HH);
            prj[u] = *(const float4*)(prb + (size_t)(j0 + 4 * u) * HH);
        }

        #pragma unroll
        for (int u = 0; u < 4; ++u) {
            float4 ap;
            ap.x = in_i.x + inj[u].x;  ap.y = in_i.y + inj[u].y;
            ap.z = in_i.z + inj[u].z;  ap.w = in_i.w + inj[u].w;
            *(float4*)(apb + (size_t)(j0 + 4 * u) * HH) = ap;
        }

        float part[4];
        #pragma unroll
        for (int u = 0; u < 4; ++u) {
            float4 v;
            v.x = pr_i.x + prj[u].x;  v.y = pr_i.y + prj[u].y;
            v.z = pr_i.z + prj[u].z;  v.w = pr_i.w + prj[u].w;
            const float* bf = &binf[(j0 + 4 * u) * NBIN];
            #pragma unroll
            for (int c = 0; c < NBIN; ++c) {
                const float bc = bf[c];    // LDS broadcast within wave
                v.x = fmaf(bc, wb[c].x, v.x);
                v.y = fmaf(bc, wb[c].y, v.y);
                v.z = fmaf(bc, wb[c].z, v.z);
                v.w = fmaf(bc, wb[c].w, v.w);
            }
            v.x = fmaxf(v.x, 0.f); v.y = fmaxf(v.y, 0.f);
            v.z = fmaxf(v.z, 0.f); v.w = fmaxf(v.w, 0.f);
            part[u] = v.x * ws.x + v.y * ws.y + v.z * ws.z + v.w * ws.w;
        }

        // four independent butterfly chains, interleaved
        #pragma unroll
        for (int off = 32; off > 0; off >>= 1) {
            #pragma unroll
            for (int u = 0; u < 4; ++u)
                part[u] += __shfl_xor(part[u], off, 64);
        }

        #pragma unroll
        for (int u = 0; u < 4; ++u) {
            const float s = 1.f / (1.f + expf(-(part[u] + bsc)));
            acc.x = fmaf(s, inj[u].x, acc.x);
            acc.y = fmaf(s, inj[u].y, acc.y);
            acc.z = fmaf(s, inj[u].z, acc.z);
            acc.w = fmaf(s, inj[u].w, acc.w);
        }
    }

    // cross-wave reduce of context accumulator
    if (wave > 0) *(float4*)(&partial[wave - 1][k4]) = acc;
    __syncthreads();
    if (wave == 0) {
        #pragma unroll
        for (int w = 0; w < 3; ++w) {
            const float4 pw = *(const float4*)(&partial[w][k4]);
            acc.x += pw.x; acc.y += pw.y; acc.z += pw.z; acc.w += pw.w;
        }
        *(float4*)(context + (size_t)bi * HH + k4) = acc;
    }
}

extern "C" void kernel_launch(void* const* d_in, const int* in_sizes, int n_in,
                              void* d_out, int out_size, void* d_ws, size_t ws_size,
                              hipStream_t stream)
{
    const float* inputs       = (const float*)d_in[0];   // (B,N,H)
    const float* bin_features = (const float*)d_in[1];   // (B,N,N,BIN)
    const float* W_atom       = (const float*)d_in[2];   // (H,H)
    const float* W_bin        = (const float*)d_in[3];   // (BIN,H)
    const float* b_bin        = (const float*)d_in[4];   // (H,)
    const float* w_score      = (const float*)d_in[5];   // (H,1)
    const float* b_score      = (const float*)d_in[6];   // (1,)

    float* context   = (float*)d_out;                         // B*N*H
    float* atom_pair = (float*)d_out + (size_t)BB * NN * HH;  // B*N*N*H

    float* proj = (float*)d_ws;                               // B*N*H floats

    proj_kernel<<<(BB * NN) / ROWS_PER_BLOCK, HH, 0, stream>>>(
        inputs, W_atom, b_bin, proj);

    pair_ctx_kernel<<<BB * NN, 256, 0, stream>>>(
        inputs, bin_features, W_bin, w_score, b_score, proj,
        atom_pair, context);
}

// Round 8
// 51.721 us; speedup vs baseline: 1.8398x; 1.0699x over previous
//
#include <hip/hip_runtime.h>
#include <math.h>

#define BB 16
#define NN 96
#define HH 256
#define NBIN 11
#define NBPAD 12   // bin row padded to 12 floats -> 48 B, 16-B aligned rows

// ---------------------------------------------------------------------------
// DPP wave64 sum: row_shr 1/2/4/8 accumulates row sums into lane 15/31/47/63,
// row_bcast:15 then row_bcast:31 combine rows; full sum lands in lane 63;
// readlane broadcasts it wave-uniformly. Pure VALU - no LDS unit traffic.
// dpp_ctrl must be an immediate -> template parameter.
// ---------------------------------------------------------------------------
template <int CTRL>
__device__ __forceinline__ float dpp_add(float x) {
    int t = __builtin_amdgcn_update_dpp(0, __float_as_int(x),
                                        CTRL, 0xf, 0xf, true);
    return x + __int_as_float(t);
}

__device__ __forceinline__ float wave64_sum_uniform(float x) {
    x = dpp_add<0x111>(x);  // row_shr:1
    x = dpp_add<0x112>(x);  // row_shr:2
    x = dpp_add<0x114>(x);  // row_shr:4
    x = dpp_add<0x118>(x);  // row_shr:8
    x = dpp_add<0x142>(x);  // row_bcast:15
    x = dpp_add<0x143>(x);  // row_bcast:31
    return __int_as_float(__builtin_amdgcn_readlane(__float_as_int(x), 63));
}

// ---------------------------------------------------------------------------
// Kernel 1: proj[r][k] = sum_h inputs[r][h] * W_atom[h][k] + 0.5*b_bin[k]
// ---------------------------------------------------------------------------
#define ROWS_PER_BLOCK 4

__global__ __launch_bounds__(HH) void proj_kernel(
    const float* __restrict__ inputs,
    const float* __restrict__ W_atom,
    const float* __restrict__ b_bin,
    float* __restrict__ proj)
{
    __shared__ float rows[ROWS_PER_BLOCK][HH];
    const int r0 = blockIdx.x * ROWS_PER_BLOCK;
    const int k  = threadIdx.x;

    #pragma unroll
    for (int r = 0; r < ROWS_PER_BLOCK; ++r)
        rows[r][k] = inputs[(size_t)(r0 + r) * HH + k];
    __syncthreads();

    float acc[ROWS_PER_BLOCK];
    #pragma unroll
    for (int r = 0; r < ROWS_PER_BLOCK; ++r) acc[r] = 0.f;

    #pragma unroll 8
    for (int h = 0; h < HH; ++h) {
        const float w = W_atom[(size_t)h * HH + k];   // coalesced over k
        #pragma unroll
        for (int r = 0; r < ROWS_PER_BLOCK; ++r)
            acc[r] = fmaf(rows[r][h], w, acc[r]);     // LDS broadcast read
    }

    const float halfb = 0.5f * b_bin[k];
    #pragma unroll
    for (int r = 0; r < ROWS_PER_BLOCK; ++r)
        proj[(size_t)(r0 + r) * HH + k] = acc[r] + halfb;
}

// ---------------------------------------------------------------------------
// Kernel 2 (fused pair + score + context): one block per (b,i); 4 waves;
//   wave owns j = wave + 4*u + 16*t (4 j's per outer step).
//   DS traffic per j: 3x ds_read_b128 (padded bin row). Reduction and
//   broadcast are DPP VALU ops. Stores plain float4, overlapped.
// ---------------------------------------------------------------------------
__global__ __launch_bounds__(256) void pair_ctx_kernel(
    const float* __restrict__ inputs,
    const float* __restrict__ bin_features,
    const float* __restrict__ W_bin,
    const float* __restrict__ w_score,
    const float* __restrict__ b_score,
    const float* __restrict__ proj,
    float* __restrict__ atom_pair,
    float* __restrict__ context)
{
    const int bi   = blockIdx.x;           // b*N + i
    const int b    = bi / NN;
    const int lane = threadIdx.x & 63;
    const int wave = threadIdx.x >> 6;     // 0..3
    const int k4   = lane << 2;            // float4 offset into H

    __shared__ float binf[NN * NBPAD];     // padded rows, 16-B aligned
    __shared__ float partial[3][HH];

    {
        const float* bp = bin_features + (size_t)bi * NN * NBIN;
        for (int t = threadIdx.x; t < NN * NBIN; t += 256)
            binf[(t / NBIN) * NBPAD + (t % NBIN)] = bp[t];
    }

    const float4 in_i = *(const float4*)(inputs + (size_t)bi * HH + k4);
    const float4 pr_i = *(const float4*)(proj   + (size_t)bi * HH + k4);
    const float4 ws   = *(const float4*)(w_score + k4);
    const float  bsc  = b_score[0];

    float4 wb[NBIN];
    #pragma unroll
    for (int c = 0; c < NBIN; ++c)
        wb[c] = *(const float4*)(W_bin + c * HH + k4);

    const float* inb = inputs + (size_t)b * NN * HH + k4;
    const float* prb = proj   + (size_t)b * NN * HH + k4;
    float*       apb = atom_pair + (size_t)bi * NN * HH + k4;

    __syncthreads();                       // binf ready

    float4 acc = make_float4(0.f, 0.f, 0.f, 0.f);

    // 96 = 4 waves * 4 unroll * 6 outer steps
    for (int t = 0; t < 6; ++t) {
        const int j0 = wave + 16 * t;

        float4 inj[4], prj[4];
        #pragma unroll
        for (int u = 0; u < 4; ++u) {
            inj[u] = *(const float4*)(inb + (size_t)(j0 + 4 * u) * HH);
            prj[u] = *(const float4*)(prb + (size_t)(j0 + 4 * u) * HH);
        }

        #pragma unroll
        for (int u = 0; u < 4; ++u) {
            float4 ap;
            ap.x = in_i.x + inj[u].x;  ap.y = in_i.y + inj[u].y;
            ap.z = in_i.z + inj[u].z;  ap.w = in_i.w + inj[u].w;
            *(float4*)(apb + (size_t)(j0 + 4 * u) * HH) = ap;
        }

        float part[4];
        #pragma unroll
        for (int u = 0; u < 4; ++u) {
            // padded bin row: 3x ds_read_b128 (element 11 is pad, unused)
            const float4* bf4 = (const float4*)&binf[(j0 + 4 * u) * NBPAD];
            const float4 bq0 = bf4[0];
            const float4 bq1 = bf4[1];
            const float4 bq2 = bf4[2];
            const float bc[NBIN] = { bq0.x, bq0.y, bq0.z, bq0.w,
                                     bq1.x, bq1.y, bq1.z, bq1.w,
                                     bq2.x, bq2.y, bq2.z };

            float4 v;
            v.x = pr_i.x + prj[u].x;  v.y = pr_i.y + prj[u].y;
            v.z = pr_i.z + prj[u].z;  v.w = pr_i.w + prj[u].w;
            #pragma unroll
            for (int c = 0; c < NBIN; ++c) {
                v.x = fmaf(bc[c], wb[c].x, v.x);
                v.y = fmaf(bc[c], wb[c].y, v.y);
                v.z = fmaf(bc[c], wb[c].z, v.z);
                v.w = fmaf(bc[c], wb[c].w, v.w);
            }
            v.x = fmaxf(v.x, 0.f); v.y = fmaxf(v.y, 0.f);
            v.z = fmaxf(v.z, 0.f); v.w = fmaxf(v.w, 0.f);
            part[u] = v.x * ws.x + v.y * ws.y + v.z * ws.z + v.w * ws.w;
        }

        // four independent DPP reduction chains (pure VALU)
        float s[4];
        #pragma unroll
        for (int u = 0; u < 4; ++u) {
            const float tot = wave64_sum_uniform(part[u]);
            s[u] = 1.f / (1.f + __expf(-(tot + bsc)));
        }

        #pragma unroll
        for (int u = 0; u < 4; ++u) {
            acc.x = fmaf(s[u], inj[u].x, acc.x);
            acc.y = fmaf(s[u], inj[u].y, acc.y);
            acc.z = fmaf(s[u], inj[u].z, acc.z);
            acc.w = fmaf(s[u], inj[u].w, acc.w);
        }
    }

    // cross-wave reduce of context accumulator
    if (wave > 0) *(float4*)(&partial[wave - 1][k4]) = acc;
    __syncthreads();
    if (wave == 0) {
        #pragma unroll
        for (int w = 0; w < 3; ++w) {
            const float4 pw = *(const float4*)(&partial[w][k4]);
            acc.x += pw.x; acc.y += pw.y; acc.z += pw.z; acc.w += pw.w;
        }
        *(float4*)(context + (size_t)bi * HH + k4) = acc;
    }
}

extern "C" void kernel_launch(void* const* d_in, const int* in_sizes, int n_in,
                              void* d_out, int out_size, void* d_ws, size_t ws_size,
                              hipStream_t stream)
{
    const float* inputs       = (const float*)d_in[0];   // (B,N,H)
    const float* bin_features = (const float*)d_in[1];   // (B,N,N,BIN)
    const float* W_atom       = (const float*)d_in[2];   // (H,H)
    const float* W_bin        = (const float*)d_in[3];   // (BIN,H)
    const float* b_bin        = (const float*)d_in[4];   // (H,)
    const float* w_score      = (const float*)d_in[5];   // (H,1)
    const float* b_score      = (const float*)d_in[6];   // (1,)

    float* context   = (float*)d_out;                         // B*N*H
    float* atom_pair = (float*)d_out + (size_t)BB * NN * HH;  // B*N*N*H

    float* proj = (float*)d_ws;                               // B*N*H floats

    proj_kernel<<<(BB * NN) / ROWS_PER_BLOCK, HH, 0, stream>>>(
        inputs, W_atom, b_bin, proj);

    pair_ctx_kernel<<<BB * NN, 256, 0, stream>>>(
        inputs, bin_features, W_bin, w_score, b_score, proj,
        atom_pair, context);
}